// Round 1
// baseline (237.995 us; speedup 1.0000x reference)
//
#include <hip/hip_runtime.h>
#include <stdint.h>

#define NROWS 8192
#define KX    2048      // N*M
#define KA    2112      // KX + NF (augmented K)
#define NF    64
#define DD    2016
#define WCOLS 2080      // NF + DD
#define ODIM  1024
#define BN_EPS 1e-5f

using f32x4  = __attribute__((ext_vector_type(4))) float;
using bf16x8 = __attribute__((ext_vector_type(8))) short;

__device__ __forceinline__ short f2bf(float x) {
    uint32_t u = __float_as_uint(x);
    uint32_t r = (u + 0x7FFFu + ((u >> 16) & 1u)) >> 16;   // RNE to bf16
    return (short)r;
}

__device__ __forceinline__ void gload16(const void* g, void* l) {
    __builtin_amdgcn_global_load_lds(
        (const __attribute__((address_space(1))) uint32_t*)g,
        (__attribute__((address_space(3))) uint32_t*)l, 16, 0, 0);
}

// ---------------------------------------------------------------------------
// Kernel 1: convert X (fp32) -> bf16 into augmented Xa[8192][2112];
// cols [0,2048) = bf16(x); cols [2048,2112) = bf16(sum_m x^2 - 32) per field.
// One block per row, 256 threads, 8 floats/thread.
// ---------------------------------------------------------------------------
__global__ __launch_bounds__(256) void convert_x(const float* __restrict__ X,
                                                 short* __restrict__ Xa) {
    const int row = blockIdx.x;
    const int t = threadIdx.x;
    const float4* xr = reinterpret_cast<const float4*>(X + (size_t)row * KX);
    float4 v0 = xr[t * 2];
    float4 v1 = xr[t * 2 + 1];
    bf16x8 s;
    s[0] = f2bf(v0.x); s[1] = f2bf(v0.y); s[2] = f2bf(v0.z); s[3] = f2bf(v0.w);
    s[4] = f2bf(v1.x); s[5] = f2bf(v1.y); s[6] = f2bf(v1.z); s[7] = f2bf(v1.w);
    short* outr = Xa + (size_t)row * KA;
    reinterpret_cast<bf16x8*>(outr)[t] = s;
    float sq = v0.x*v0.x + v0.y*v0.y + v0.z*v0.z + v0.w*v0.w
             + v1.x*v1.x + v1.y*v1.y + v1.z*v1.z + v1.w*v1.w;
    sq += __shfl_xor(sq, 1);
    sq += __shfl_xor(sq, 2);
    if ((t & 3) == 0) outr[KX + (t >> 2)] = f2bf(sq - 32.0f);  // centered
}

// ---------------------------------------------------------------------------
// Kernel 2: A1[o][k] = sum_{d<64} Wa[o][d] * Wz[d][k]  -> bf16 Aw[o][0..2048)
// grid (2048/256, 1024), one thread per (o,k).
// ---------------------------------------------------------------------------
__global__ __launch_bounds__(256) void build_a1(const float* __restrict__ Wa,
                                                const float* __restrict__ Wz,
                                                short* __restrict__ Aw) {
    const int o = blockIdx.y;
    const int k = blockIdx.x * 256 + threadIdx.x;
    const float* war = Wa + (size_t)o * WCOLS;
    float acc = 0.f;
#pragma unroll 16
    for (int d = 0; d < 64; ++d) acc += war[d] * Wz[d * KX + k];
    Aw[(size_t)o * KA + k] = f2bf(acc);
}

// ---------------------------------------------------------------------------
// Kernel 3: A2[o][n] = sum_{d<2016} Wa[o][64+d] * theta[d][n]^2
//           -> bf16 Aw[o][2048+n]. One block per o, 4 d-groups x 64 n-lanes.
// ---------------------------------------------------------------------------
__global__ __launch_bounds__(256) void build_a2(const float* __restrict__ Wa,
                                                const float* __restrict__ theta,
                                                short* __restrict__ Aw) {
    const int o = blockIdx.x;
    const int n = threadIdx.x & 63;
    const int g = threadIdx.x >> 6;
    const float* war = Wa + (size_t)o * WCOLS + NF;
    float acc = 0.f;
    for (int d = g; d < DD; d += 4) {
        float th = theta[d * NF + n];
        acc += war[d] * th * th;
    }
    __shared__ float red[4][64];
    red[g][n] = acc;
    __syncthreads();
    if (threadIdx.x < 64) {
        float s = red[0][threadIdx.x] + red[1][threadIdx.x] +
                  red[2][threadIdx.x] + red[3][threadIdx.x];
        Aw[(size_t)o * KA + KX + threadIdx.x] = f2bf(s);
    }
}

// ---------------------------------------------------------------------------
// Kernel 4: main GEMM  C[8192][1024] = Xa(8192x2112,bf16) * Aw(1024x2112,bf16)^T + bias
// m97 structure: 128x128 tile, BK=32, 4 waves (2x2), 16x16x32 bf16 MFMA,
// global_load_lds width 16, 2-bit XOR slot swizzle (both-sides).
// ---------------------------------------------------------------------------
__global__ __launch_bounds__(256) void gemm_kern(const short* __restrict__ Xa,
                                                 const short* __restrict__ Aw,
                                                 const float* __restrict__ bias,
                                                 float* __restrict__ C) {
    __shared__ __align__(16) short As[128 * 32];
    __shared__ __align__(16) short Bs[128 * 32];
    const int tid  = threadIdx.x;
    const int lane = tid & 63;
    const int wid  = tid >> 6;
    const int wr = wid >> 1, wc = wid & 1;
    const int bm = blockIdx.x * 128;
    const int bn = blockIdx.y * 128;

    f32x4 acc[4][4] = {};

    // Staging: chunk c (16B) at LDS pos c holds global slot q = (c&3) ^ f(r),
    // r = c>>2, f(r) = (r>>1)&3.  Linear LDS dest (global_load_lds rule).
    const int c0 = tid, c1 = tid + 256;
    const int r0 = c0 >> 2, q0 = (c0 & 3) ^ ((r0 >> 1) & 3);
    const int r1 = c1 >> 2, q1 = (c1 & 3) ^ ((r1 >> 1) & 3);
    const short* gA0 = Xa + (size_t)(bm + r0) * KA + q0 * 8;
    const short* gA1 = Xa + (size_t)(bm + r1) * KA + q1 * 8;
    const short* gB0 = Aw + (size_t)(bn + r0) * KA + q0 * 8;
    const short* gB1 = Aw + (size_t)(bn + r1) * KA + q1 * 8;
    short* lA0 = As + c0 * 8;  short* lA1 = As + c1 * 8;
    short* lB0 = Bs + c0 * 8;  short* lB1 = Bs + c1 * 8;

    // LDS read offsets (swizzled): lane needs logical slot lq = lane>>4 of row r.
    const int lq = lane >> 4;
    int offA[4], offB[4];
#pragma unroll
    for (int m = 0; m < 4; ++m) {
        int ra = wr * 64 + m * 16 + (lane & 15);
        offA[m] = ra * 32 + (lq ^ ((ra >> 1) & 3)) * 8;
        int rb = wc * 64 + m * 16 + (lane & 15);
        offB[m] = rb * 32 + (lq ^ ((rb >> 1) & 3)) * 8;
    }

    for (int kt = 0; kt < KA / 32; ++kt) {
        const int ko = kt * 32;
        gload16(gA0 + ko, lA0);
        gload16(gA1 + ko, lA1);
        gload16(gB0 + ko, lB0);
        gload16(gB1 + ko, lB1);
        __syncthreads();
        bf16x8 a[4], b[4];
#pragma unroll
        for (int m = 0; m < 4; ++m) a[m] = *reinterpret_cast<const bf16x8*>(As + offA[m]);
#pragma unroll
        for (int n = 0; n < 4; ++n) b[n] = *reinterpret_cast<const bf16x8*>(Bs + offB[n]);
#pragma unroll
        for (int m = 0; m < 4; ++m)
#pragma unroll
            for (int n = 0; n < 4; ++n)
                acc[m][n] = __builtin_amdgcn_mfma_f32_16x16x32_bf16(a[m], b[n], acc[m][n], 0, 0, 0);
        __syncthreads();
    }

    // Epilogue: C/D layout col=lane&15, row=(lane>>4)*4+reg  (m89/m91 verified)
    const int rlo = (lane >> 4) * 4;
    const int cl  = lane & 15;
#pragma unroll
    for (int n = 0; n < 4; ++n) {
        const int col = bn + wc * 64 + n * 16 + cl;
        const float bv = bias[col];
#pragma unroll
        for (int m = 0; m < 4; ++m) {
            const int rowb = bm + wr * 64 + m * 16 + rlo;
#pragma unroll
            for (int r2 = 0; r2 < 4; ++r2)
                C[(size_t)(rowb + r2) * ODIM + col] = acc[m][n][r2] + bv;
        }
    }
}

// ---------------------------------------------------------------------------
// Kernel 5: BN column sums (sum, sumsq) via per-block partials + atomics.
// 256 blocks x 32 rows; thread t owns cols {t, t+256, t+512, t+768}.
// ---------------------------------------------------------------------------
__global__ __launch_bounds__(256) void bn_stats(const float* __restrict__ C,
                                                float* __restrict__ sums) {
    const int t = threadIdx.x;
    const int row0 = blockIdx.x * 32;
    float s[4] = {0, 0, 0, 0}, sq[4] = {0, 0, 0, 0};
    for (int r = 0; r < 32; ++r) {
        const float* rowp = C + (size_t)(row0 + r) * ODIM;
#pragma unroll
        for (int j = 0; j < 4; ++j) {
            float v = rowp[t + j * 256];
            s[j] += v; sq[j] += v * v;
        }
    }
#pragma unroll
    for (int j = 0; j < 4; ++j) {
        atomicAdd(&sums[t + j * 256], s[j]);
        atomicAdd(&sums[ODIM + t + j * 256], sq[j]);
    }
}

// Kernel 6: scale/shift per column
__global__ __launch_bounds__(256) void bn_finalize(float* __restrict__ sums,
                                                   const float* __restrict__ gamma,
                                                   const float* __restrict__ beta) {
    const int c = blockIdx.x * 256 + threadIdx.x;
    const float inv = 1.0f / (float)NROWS;
    float mean = sums[c] * inv;
    float var  = sums[ODIM + c] * inv - mean * mean;
    float sc   = gamma[c] * rsqrtf(var + BN_EPS);
    sums[2 * ODIM + c] = sc;
    sums[3 * ODIM + c] = beta[c] - mean * sc;
}

// Kernel 7: apply BN in place (float4)
__global__ __launch_bounds__(256) void bn_apply(float* __restrict__ C,
                                                const float* __restrict__ sums) {
    const float4* sc4 = reinterpret_cast<const float4*>(sums + 2 * ODIM);
    const float4* sh4 = reinterpret_cast<const float4*>(sums + 3 * ODIM);
    const size_t total = (size_t)NROWS * (ODIM / 4);
    for (size_t i = (size_t)blockIdx.x * 256 + threadIdx.x; i < total;
         i += (size_t)gridDim.x * 256) {
        const int c4 = (int)(i & (ODIM / 4 - 1));
        float4 v = reinterpret_cast<const float4*>(C)[i];
        float4 s = sc4[c4], h = sh4[c4];
        v.x = v.x * s.x + h.x;
        v.y = v.y * s.y + h.y;
        v.z = v.z * s.z + h.z;
        v.w = v.w * s.w + h.w;
        reinterpret_cast<float4*>(C)[i] = v;
    }
}

// ---------------------------------------------------------------------------
extern "C" void kernel_launch(void* const* d_in, const int* in_sizes, int n_in,
                              void* d_out, int out_size, void* d_ws, size_t ws_size,
                              hipStream_t stream) {
    const float* X     = (const float*)d_in[0];
    const float* Wz    = (const float*)d_in[1];
    const float* theta = (const float*)d_in[2];
    const float* Wa    = (const float*)d_in[3];
    const float* bias  = (const float*)d_in[4];
    const float* gamma = (const float*)d_in[5];
    const float* beta  = (const float*)d_in[6];
    float* out = (float*)d_out;

    char* ws = (char*)d_ws;
    float* sums = (float*)ws;                                   // 4096 floats
    short* Xa = (short*)(ws + 16384);                           // 8192*2112 bf16
    short* Aw = (short*)(ws + 16384 + (size_t)NROWS * KA * 2);  // 1024*2112 bf16

    hipMemsetAsync(sums, 0, 2 * ODIM * sizeof(float), stream);
    convert_x<<<NROWS, 256, 0, stream>>>(X, Xa);
    build_a1<<<dim3(KX / 256, ODIM), 256, 0, stream>>>(Wa, Wz, Aw);
    build_a2<<<ODIM, 256, 0, stream>>>(Wa, theta, Aw);
    gemm_kern<<<dim3(NROWS / 128, ODIM / 128), 256, 0, stream>>>(Xa, Aw, bias, out);
    bn_stats<<<256, 256, 0, stream>>>(out, sums);
    bn_finalize<<<ODIM / 256, 256, 0, stream>>>(sums, gamma, beta);
    bn_apply<<<2048, 256, 0, stream>>>(out, sums);
}

// Round 2
// 146.799 us; speedup vs baseline: 1.6212x; 1.6212x over previous
//
#include <hip/hip_runtime.h>
#include <stdint.h>

#define NROWS 8192
#define KX    2048      // N*M
#define KA    2112      // KX + NF (augmented K)
#define NF    64
#define DD    2016
#define WCOLS 2080      // NF + DD
#define ODIM  1024
#define BN_EPS 1e-5f

#define DCHUNKS 12
#define DPC     168     // DD / DCHUNKS

using f32x4  = __attribute__((ext_vector_type(4))) float;
using bf16x8 = __attribute__((ext_vector_type(8))) short;

__device__ __forceinline__ short f2bf(float x) {
    uint32_t u = __float_as_uint(x);
    uint32_t r = (u + 0x7FFFu + ((u >> 16) & 1u)) >> 16;   // RNE to bf16
    return (short)r;
}

__device__ __forceinline__ void gload16(const void* g, void* l) {
    __builtin_amdgcn_global_load_lds(
        (const __attribute__((address_space(1))) uint32_t*)g,
        (__attribute__((address_space(3))) uint32_t*)l, 16, 0, 0);
}

// ---------------------------------------------------------------------------
// Kernel 1: convert X (fp32) -> bf16 into augmented Xa[8192][2112];
// cols [0,2048) = bf16(x); cols [2048,2112) = bf16(sum_m x^2 - 32) per field.
// ---------------------------------------------------------------------------
__global__ __launch_bounds__(256) void convert_x(const float* __restrict__ X,
                                                 short* __restrict__ Xa) {
    const int row = blockIdx.x;
    const int t = threadIdx.x;
    const float4* xr = reinterpret_cast<const float4*>(X + (size_t)row * KX);
    float4 v0 = xr[t * 2];
    float4 v1 = xr[t * 2 + 1];
    bf16x8 s;
    s[0] = f2bf(v0.x); s[1] = f2bf(v0.y); s[2] = f2bf(v0.z); s[3] = f2bf(v0.w);
    s[4] = f2bf(v1.x); s[5] = f2bf(v1.y); s[6] = f2bf(v1.z); s[7] = f2bf(v1.w);
    short* outr = Xa + (size_t)row * KA;
    reinterpret_cast<bf16x8*>(outr)[t] = s;
    float sq = v0.x*v0.x + v0.y*v0.y + v0.z*v0.z + v0.w*v0.w
             + v1.x*v1.x + v1.y*v1.y + v1.z*v1.z + v1.w*v1.w;
    sq += __shfl_xor(sq, 1);
    sq += __shfl_xor(sq, 2);
    if ((t & 3) == 0) outr[KX + (t >> 2)] = f2bf(sq - 32.0f);  // centered
}

// ---------------------------------------------------------------------------
// Kernel 2: A1[o][k] = sum_{d<64} Wa[o][d] * Wz[d][k]  -> bf16 Aw[o][0..2048)
// ---------------------------------------------------------------------------
__global__ __launch_bounds__(256) void build_a1(const float* __restrict__ Wa,
                                                const float* __restrict__ Wz,
                                                short* __restrict__ Aw) {
    const int o = blockIdx.y;
    const int k = blockIdx.x * 256 + threadIdx.x;
    const float* war = Wa + (size_t)o * WCOLS;
    float acc = 0.f;
#pragma unroll 16
    for (int d = 0; d < 64; ++d) acc += war[d] * Wz[d * KX + k];
    Aw[(size_t)o * KA + k] = f2bf(acc);
}

// ---------------------------------------------------------------------------
// Kernel 3a: A2 partials. grid (DCHUNKS, ODIM); block = 4 d-groups x 64 n.
// partials[chunk][o][n] = sum over this chunk's d of Wa2[o][d]*theta[d][n]^2.
// d-parallelism 12x vs round-1 (chain 504 -> 42 iters, 12288 blocks).
// ---------------------------------------------------------------------------
__global__ __launch_bounds__(256) void build_a2(const float* __restrict__ Wa,
                                                const float* __restrict__ theta,
                                                float* __restrict__ partials) {
    const int o = blockIdx.y;
    const int chunk = blockIdx.x;
    const int n = threadIdx.x & 63;
    const int g = threadIdx.x >> 6;
    const float* war = Wa + (size_t)o * WCOLS + NF;
    const int d0 = chunk * DPC;
    float acc = 0.f;
#pragma unroll 6
    for (int i = g; i < DPC; i += 4) {
        const int d = d0 + i;
        float th = theta[d * NF + n];
        acc += war[d] * th * th;
    }
    __shared__ float red[4][64];
    red[g][n] = acc;
    __syncthreads();
    if (threadIdx.x < 64) {
        float s = red[0][threadIdx.x] + red[1][threadIdx.x] +
                  red[2][threadIdx.x] + red[3][threadIdx.x];
        partials[((size_t)chunk * ODIM + o) * NF + threadIdx.x] = s;
    }
}

// Kernel 3b: reduce 12 partials -> bf16 Aw cols [2048,2112). 65536 outputs.
__global__ __launch_bounds__(256) void a2_reduce(const float* __restrict__ partials,
                                                 short* __restrict__ Aw) {
    const int idx = blockIdx.x * 256 + threadIdx.x;   // o*64+n
    const int o = idx >> 6, n = idx & 63;
    float s = 0.f;
#pragma unroll
    for (int c = 0; c < DCHUNKS; ++c)
        s += partials[((size_t)c * ODIM + o) * NF + n];
    Aw[(size_t)o * KA + KX + n] = f2bf(s);
}

// ---------------------------------------------------------------------------
// Kernel 4: main GEMM  C[8192][1024] = Xa * Aw^T + bias  (m97 structure)
// ---------------------------------------------------------------------------
__global__ __launch_bounds__(256) void gemm_kern(const short* __restrict__ Xa,
                                                 const short* __restrict__ Aw,
                                                 const float* __restrict__ bias,
                                                 float* __restrict__ C) {
    __shared__ __align__(16) short As[128 * 32];
    __shared__ __align__(16) short Bs[128 * 32];
    const int tid  = threadIdx.x;
    const int lane = tid & 63;
    const int wid  = tid >> 6;
    const int wr = wid >> 1, wc = wid & 1;
    const int bm = blockIdx.x * 128;
    const int bn = blockIdx.y * 128;

    f32x4 acc[4][4] = {};

    const int c0 = tid, c1 = tid + 256;
    const int r0 = c0 >> 2, q0 = (c0 & 3) ^ ((r0 >> 1) & 3);
    const int r1 = c1 >> 2, q1 = (c1 & 3) ^ ((r1 >> 1) & 3);
    const short* gA0 = Xa + (size_t)(bm + r0) * KA + q0 * 8;
    const short* gA1 = Xa + (size_t)(bm + r1) * KA + q1 * 8;
    const short* gB0 = Aw + (size_t)(bn + r0) * KA + q0 * 8;
    const short* gB1 = Aw + (size_t)(bn + r1) * KA + q1 * 8;
    short* lA0 = As + c0 * 8;  short* lA1 = As + c1 * 8;
    short* lB0 = Bs + c0 * 8;  short* lB1 = Bs + c1 * 8;

    const int lq = lane >> 4;
    int offA[4], offB[4];
#pragma unroll
    for (int m = 0; m < 4; ++m) {
        int ra = wr * 64 + m * 16 + (lane & 15);
        offA[m] = ra * 32 + (lq ^ ((ra >> 1) & 3)) * 8;
        int rb = wc * 64 + m * 16 + (lane & 15);
        offB[m] = rb * 32 + (lq ^ ((rb >> 1) & 3)) * 8;
    }

    for (int kt = 0; kt < KA / 32; ++kt) {
        const int ko = kt * 32;
        gload16(gA0 + ko, lA0);
        gload16(gA1 + ko, lA1);
        gload16(gB0 + ko, lB0);
        gload16(gB1 + ko, lB1);
        __syncthreads();
        bf16x8 a[4], b[4];
#pragma unroll
        for (int m = 0; m < 4; ++m) a[m] = *reinterpret_cast<const bf16x8*>(As + offA[m]);
#pragma unroll
        for (int n = 0; n < 4; ++n) b[n] = *reinterpret_cast<const bf16x8*>(Bs + offB[n]);
#pragma unroll
        for (int m = 0; m < 4; ++m)
#pragma unroll
            for (int n = 0; n < 4; ++n)
                acc[m][n] = __builtin_amdgcn_mfma_f32_16x16x32_bf16(a[m], b[n], acc[m][n], 0, 0, 0);
        __syncthreads();
    }

    const int rlo = (lane >> 4) * 4;
    const int cl  = lane & 15;
#pragma unroll
    for (int n = 0; n < 4; ++n) {
        const int col = bn + wc * 64 + n * 16 + cl;
        const float bv = bias[col];
#pragma unroll
        for (int m = 0; m < 4; ++m) {
            const int rowb = bm + wr * 64 + m * 16 + rlo;
#pragma unroll
            for (int r2 = 0; r2 < 4; ++r2)
                C[(size_t)(rowb + r2) * ODIM + col] = acc[m][n][r2] + bv;
        }
    }
}

// ---------------------------------------------------------------------------
// Kernel 5: BN column sums (sum, sumsq)
// ---------------------------------------------------------------------------
__global__ __launch_bounds__(256) void bn_stats(const float* __restrict__ C,
                                                float* __restrict__ sums) {
    const int t = threadIdx.x;
    const int row0 = blockIdx.x * 32;
    float s[4] = {0, 0, 0, 0}, sq[4] = {0, 0, 0, 0};
    for (int r = 0; r < 32; ++r) {
        const float* rowp = C + (size_t)(row0 + r) * ODIM;
#pragma unroll
        for (int j = 0; j < 4; ++j) {
            float v = rowp[t + j * 256];
            s[j] += v; sq[j] += v * v;
        }
    }
#pragma unroll
    for (int j = 0; j < 4; ++j) {
        atomicAdd(&sums[t + j * 256], s[j]);
        atomicAdd(&sums[ODIM + t + j * 256], sq[j]);
    }
}

// Kernel 6: scale/shift per column
__global__ __launch_bounds__(256) void bn_finalize(float* __restrict__ sums,
                                                   const float* __restrict__ gamma,
                                                   const float* __restrict__ beta) {
    const int c = blockIdx.x * 256 + threadIdx.x;
    const float inv = 1.0f / (float)NROWS;
    float mean = sums[c] * inv;
    float var  = sums[ODIM + c] * inv - mean * mean;
    float sc   = gamma[c] * rsqrtf(var + BN_EPS);
    sums[2 * ODIM + c] = sc;
    sums[3 * ODIM + c] = beta[c] - mean * sc;
}

// Kernel 7: apply BN in place (float4)
__global__ __launch_bounds__(256) void bn_apply(float* __restrict__ C,
                                                const float* __restrict__ sums) {
    const float4* sc4 = reinterpret_cast<const float4*>(sums + 2 * ODIM);
    const float4* sh4 = reinterpret_cast<const float4*>(sums + 3 * ODIM);
    const size_t total = (size_t)NROWS * (ODIM / 4);
    for (size_t i = (size_t)blockIdx.x * 256 + threadIdx.x; i < total;
         i += (size_t)gridDim.x * 256) {
        const int c4 = (int)(i & (ODIM / 4 - 1));
        float4 v = reinterpret_cast<const float4*>(C)[i];
        float4 s = sc4[c4], h = sh4[c4];
        v.x = v.x * s.x + h.x;
        v.y = v.y * s.y + h.y;
        v.z = v.z * s.z + h.z;
        v.w = v.w * s.w + h.w;
        reinterpret_cast<float4*>(C)[i] = v;
    }
}

// ---------------------------------------------------------------------------
extern "C" void kernel_launch(void* const* d_in, const int* in_sizes, int n_in,
                              void* d_out, int out_size, void* d_ws, size_t ws_size,
                              hipStream_t stream) {
    const float* X     = (const float*)d_in[0];
    const float* Wz    = (const float*)d_in[1];
    const float* theta = (const float*)d_in[2];
    const float* Wa    = (const float*)d_in[3];
    const float* bias  = (const float*)d_in[4];
    const float* gamma = (const float*)d_in[5];
    const float* beta  = (const float*)d_in[6];
    float* out = (float*)d_out;

    char* ws = (char*)d_ws;
    float* sums = (float*)ws;                                        // 4*1024 floats
    short* Xa = (short*)(ws + 16384);                                // 8192*2112 bf16
    short* Aw = (short*)(ws + 16384 + (size_t)NROWS * KA * 2);       // 1024*2112 bf16
    float* partials = (float*)(ws + 16384 + (size_t)NROWS * KA * 2
                                        + (size_t)ODIM * KA * 2);    // 12*1024*64 f32

    hipMemsetAsync(sums, 0, 2 * ODIM * sizeof(float), stream);
    convert_x<<<NROWS, 256, 0, stream>>>(X, Xa);
    build_a1<<<dim3(KX / 256, ODIM), 256, 0, stream>>>(Wa, Wz, Aw);
    build_a2<<<dim3(DCHUNKS, ODIM), 256, 0, stream>>>(Wa, theta, partials);
    a2_reduce<<<ODIM * NF / 256, 256, 0, stream>>>(partials, Aw);
    gemm_kern<<<dim3(NROWS / 128, ODIM / 128), 256, 0, stream>>>(Xa, Aw, bias, out);
    bn_stats<<<256, 256, 0, stream>>>(out, sums);
    bn_finalize<<<ODIM / 256, 256, 0, stream>>>(sums, gamma, beta);
    bn_apply<<<2048, 256, 0, stream>>>(out, sums);
}